// Round 1
// 93.675 us; speedup vs baseline: 1.0468x; 1.0468x over previous
//
#include <hip/hip_runtime.h>

typedef short s16x8 __attribute__((ext_vector_type(8)));
typedef float f32x4 __attribute__((ext_vector_type(4)));

#define NB      1024
#define NCLASS  50
#define NCENTER 8
#define HID     512
#define KPAD    64

// workspace byte offsets (16B aligned)
#define OFF_WT     0u          // 512*512*2 = 524288
#define OFF_MUBF   524288u     // 8*64*512*2 = 524288
#define OFF_MUNORM 1048576u    // 8*64*4 = 2048
// total ~1.05 MB (was 20 MB: Abf/mulbf/score eliminated)

// output layout (element offsets in d_out, fp32)
#define OUT_KA 4194304   // after mul [1024*8*512]
#define OUT_D  4603904   // after k_assign [1024*50*8]

__device__ __forceinline__ short f2bf(float f) {
    unsigned int u = __float_as_uint(f);
    unsigned int r = (u + 0x7FFFu + ((u >> 16) & 1u)) >> 16;  // RNE
    return (short)(unsigned short)r;
}

// ---------------------------------------------------------------------------
// Kernel 1: prep. blocks [0,64): W^T -> bf16 (LDS transpose);
// [64,192): class_mu -> padded bf16 + fp32 norms. (A-materialization removed:
// gemm now builds A = x*mask on the fly.)
// ---------------------------------------------------------------------------
__global__ __launch_bounds__(256) void prep_kernel(
    const float* __restrict__ class_mu, const float* __restrict__ W,
    short* __restrict__ WT, short* __restrict__ Mubf, float* __restrict__ Munorm)
{
    __shared__ float lds[64][65];
    const int blk = blockIdx.x, tid = threadIdx.x;

    if (blk < 64) {
        // WT[d][h] = bf16(W[h][d]), 64x64 tile per block
        int th = blk & 7, td = blk >> 3;          // h-tile, d-tile
        int col = tid & 63, rb = tid >> 6;
        #pragma unroll
        for (int it = 0; it < 16; ++it) {
            int row = it * 4 + rb;
            lds[row][col] = W[(th * 64 + row) * HID + td * 64 + col];
        }
        __syncthreads();
        #pragma unroll
        for (int it = 0; it < 16; ++it) {
            int row = it * 4 + rb;
            WT[(td * 64 + row) * HID + th * 64 + col] = f2bf(lds[col][row]);
        }
    } else {
        // one wave per (c, kk): Mubf[c][kk][h] (kk>=50 zero-padded), Munorm
        int w = (blk - 64) * 4 + (tid >> 6);   // 0..511
        int lane = tid & 63;
        int c = w >> 6, kk = w & 63;
        int h = lane * 8;
        float v[8];
        if (kk < NCLASS) {
            const float4* p = (const float4*)(class_mu + (kk * NCENTER + c) * HID + h);
            float4 a = p[0], bq = p[1];
            v[0] = a.x;  v[1] = a.y;  v[2] = a.z;  v[3] = a.w;
            v[4] = bq.x; v[5] = bq.y; v[6] = bq.z; v[7] = bq.w;
        } else {
            #pragma unroll
            for (int j = 0; j < 8; ++j) v[j] = 0.f;
        }
        s16x8 o; float sq = 0.f;
        #pragma unroll
        for (int j = 0; j < 8; ++j) { o[j] = f2bf(v[j]); sq += v[j] * v[j]; }
        *(s16x8*)(Mubf + (c * KPAD + kk) * HID + h) = o;
        sq += __shfl_xor(sq, 1);  sq += __shfl_xor(sq, 2);  sq += __shfl_xor(sq, 4);
        sq += __shfl_xor(sq, 8);  sq += __shfl_xor(sq, 16); sq += __shfl_xor(sq, 32);
        if (lane == 0) Munorm[c * KPAD + kk] = sq;
    }
}

// ---------------------------------------------------------------------------
// Kernel 2: mul = A @ W, A built on the fly: A[(b*8+c),k] = bf16(x[b,k]*mask[c,k]).
// BM=64 x BN=128 tile -> grid (128,4) = 512 blocks = 2 blocks/CU (was 1).
// 4 waves 2x2; each wave 32x64 via 2x4 of 16x16x32. Next-iter globals
// prefetched into regs before the barrier pair. Writes fp32 mul only.
// ---------------------------------------------------------------------------
__global__ __launch_bounds__(256) void gemm_mul(
    const float* __restrict__ x, const float* __restrict__ mask,
    const short* __restrict__ WT, float* __restrict__ mul_out)
{
    __shared__ short As[64 * 32];
    __shared__ short Bs[128 * 32];
    const int tid = threadIdx.x;
    const int bm = blockIdx.x * 64;    // M block (8192/64 = 128)
    const int bn = blockIdx.y * 128;   // N block (512/128 = 4)
    const int wave = tid >> 6, lane = tid & 63;
    const int wm = (wave & 1) * 32, wn = (wave >> 1) * 64;
    const int q = lane >> 4, l16 = lane & 15;

    f32x4 acc[2][4] = {};

    // staging: thread -> A row r0 (8 elems at c0), B rows r0 and r0+64
    const int r0 = tid >> 2, c0 = (tid & 3) * 8;
    const int xr = (bm >> 3) + (r0 >> 3);   // x row feeding A row r0 (c = r0&7)
    const float* xp = x + xr * HID + c0;
    const float* mp = mask + (r0 & 7) * HID + c0;
    const short* wp = WT + (bn + r0) * HID + c0;

    float4 xa, xb, ma, mb; s16x8 w0, w1;
#define GLOAD(IT) do { const int kq = (IT) * 32; \
        xa = *(const float4*)(xp + kq); xb = *(const float4*)(xp + kq + 4); \
        ma = *(const float4*)(mp + kq); mb = *(const float4*)(mp + kq + 4); \
        w0 = *(const s16x8*)(wp + kq);  w1 = *(const s16x8*)(wp + 64 * HID + kq); } while (0)

    GLOAD(0);
    #pragma unroll
    for (int it = 0; it < 16; ++it) {
        s16x8 oa;
        oa[0] = f2bf(xa.x * ma.x); oa[1] = f2bf(xa.y * ma.y);
        oa[2] = f2bf(xa.z * ma.z); oa[3] = f2bf(xa.w * ma.w);
        oa[4] = f2bf(xb.x * mb.x); oa[5] = f2bf(xb.y * mb.y);
        oa[6] = f2bf(xb.z * mb.z); oa[7] = f2bf(xb.w * mb.w);
        s16x8 cw0 = w0, cw1 = w1;
        if (it < 15) GLOAD(it + 1);        // prefetch next tile into regs

        __syncthreads();                   // prev iter's LDS reads done
        *(s16x8*)(As + r0 * 32 + c0)        = oa;
        *(s16x8*)(Bs + r0 * 32 + c0)        = cw0;
        *(s16x8*)(Bs + (r0 + 64) * 32 + c0) = cw1;
        __syncthreads();

        s16x8 af[2], bfr[4];
        #pragma unroll
        for (int mt = 0; mt < 2; ++mt)
            af[mt] = *(const s16x8*)(As + (wm + mt * 16 + l16) * 32 + q * 8);
        #pragma unroll
        for (int nt = 0; nt < 4; ++nt)
            bfr[nt] = *(const s16x8*)(Bs + (wn + nt * 16 + l16) * 32 + q * 8);
        #pragma unroll
        for (int mt = 0; mt < 2; ++mt)
            #pragma unroll
            for (int nt = 0; nt < 4; ++nt)
                acc[mt][nt] = __builtin_amdgcn_mfma_f32_16x16x32_bf16(af[mt], bfr[nt], acc[mt][nt], 0, 0, 0);
    }
#undef GLOAD

    // epilogue: C/D layout col=lane&15, row=(lane>>4)*4+reg
    #pragma unroll
    for (int mt = 0; mt < 2; ++mt)
        #pragma unroll
        for (int nt = 0; nt < 4; ++nt)
            #pragma unroll
            for (int reg = 0; reg < 4; ++reg) {
                int gr = bm + wm + mt * 16 + q * 4 + reg;
                int gc = bn + wn + nt * 16 + l16;
                mul_out[gr * HID + gc] = acc[mt][nt][reg];
            }
}

// ---------------------------------------------------------------------------
// Kernel 3: fused score + normalize. Block = 512 thr (8 waves), grid 256 =
// 64 b-tiles x 4 class-tiles. Wave w = center c: dot(mul_row(b,c), mu[c][k])
// for 16 b-rows x 16 classes via MFMA, row norms in fp32 on the fly, score ->
// LDS [16][16][9], then in-block normalize over the 8 centers and write
// k_assign + distances directly (norm_kernel + score buffer eliminated).
// ---------------------------------------------------------------------------
__global__ __launch_bounds__(512) void score_norm_kernel(
    const float* __restrict__ mul, const short* __restrict__ Mubf,
    const float* __restrict__ Munorm, float* __restrict__ out)
{
    __shared__ float sc[16][16][9];   // [b][k][c], pad 9 -> conflict-free writes
    const int tid = threadIdx.x;
    const int bt = blockIdx.x >> 2, kt = blockIdx.x & 3;
    const int b0 = bt * 16, kbase = kt * 16;
    const int c = tid >> 6;                 // wave = center
    const int lane = tid & 63;
    const int q = lane >> 4, l16 = lane & 15;

    f32x4 acc = {};
    float nrm = 0.f;

    const float* arow = mul + ((b0 + l16) * NCENTER + c) * HID + q * 8;
    const short* brow = Mubf + (c * KPAD + kbase + l16) * HID + q * 8;

    #pragma unroll 4
    for (int it = 0; it < 16; ++it) {
        const int k0 = it * 32;
        float4 a0 = *(const float4*)(arow + k0);
        float4 a1 = *(const float4*)(arow + k0 + 4);
        s16x8 bv = *(const s16x8*)(brow + k0);
        s16x8 av;
        av[0] = f2bf(a0.x); av[1] = f2bf(a0.y); av[2] = f2bf(a0.z); av[3] = f2bf(a0.w);
        av[4] = f2bf(a1.x); av[5] = f2bf(a1.y); av[6] = f2bf(a1.z); av[7] = f2bf(a1.w);
        nrm += a0.x * a0.x + a0.y * a0.y + a0.z * a0.z + a0.w * a0.w
             + a1.x * a1.x + a1.y * a1.y + a1.z * a1.z + a1.w * a1.w;
        acc = __builtin_amdgcn_mfma_f32_16x16x32_bf16(av, bv, acc, 0, 0, 0);
    }

    // full row norm: lane (q,l16) covered k-chunk q; xor over q
    nrm += __shfl_xor(nrm, 16);
    nrm += __shfl_xor(nrm, 32);

    float mn = Munorm[c * KPAD + kbase + l16];
    #pragma unroll
    for (int reg = 0; reg < 4; ++reg) {
        float rn = __shfl(nrm, q * 4 + reg);         // norm of row q*4+reg
        float sq = rn + mn - 2.f * acc[reg];
        sc[q * 4 + reg][l16][c] = 1.f / (1.f + sq);
    }
    __syncthreads();

    if (tid < 256) {
        int b = tid >> 4, k = tid & 15;
        int kcls = kbase + k;
        if (kcls < NCLASS) {
            float s0 = sc[b][k][0], s1 = sc[b][k][1], s2 = sc[b][k][2], s3 = sc[b][k][3];
            float s4 = sc[b][k][4], s5 = sc[b][k][5], s6 = sc[b][k][6], s7 = sc[b][k][7];
            float S = ((s0 + s1) + (s2 + s3)) + ((s4 + s5) + (s6 + s7));
            float invd = 1.f / (S + 1e-8f);   // distances = score/(S+eps)
            float invk = 1.f / S;             // k_assign  = score/S
            float* kap = out + OUT_KA + ((b0 + b) * NCLASS + kcls) * NCENTER;
            float* dp  = out + OUT_D  + ((b0 + b) * NCLASS + kcls) * NCENTER;
            float4 ka0 = {s0 * invk, s1 * invk, s2 * invk, s3 * invk};
            float4 ka1 = {s4 * invk, s5 * invk, s6 * invk, s7 * invk};
            float4 dd0 = {s0 * invd, s1 * invd, s2 * invd, s3 * invd};
            float4 dd1 = {s4 * invd, s5 * invd, s6 * invd, s7 * invd};
            ((float4*)kap)[0] = ka0; ((float4*)kap)[1] = ka1;
            ((float4*)dp)[0]  = dd0; ((float4*)dp)[1]  = dd1;
        }
    }
}

extern "C" void kernel_launch(void* const* d_in, const int* in_sizes, int n_in,
                              void* d_out, int out_size, void* d_ws, size_t ws_size,
                              hipStream_t stream) {
    const float* x        = (const float*)d_in[0];
    const float* class_mu = (const float*)d_in[1];
    const float* mask     = (const float*)d_in[2];
    const float* W        = (const float*)d_in[3];
    float* out = (float*)d_out;
    char* ws = (char*)d_ws;

    short* WT     = (short*)(ws + OFF_WT);
    short* Mubf   = (short*)(ws + OFF_MUBF);
    float* Munorm = (float*)(ws + OFF_MUNORM);

    prep_kernel<<<192, 256, 0, stream>>>(class_mu, W, WT, Mubf, Munorm);
    gemm_mul<<<dim3(128, 4), 256, 0, stream>>>(x, mask, WT, out);
    score_norm_kernel<<<256, 512, 0, stream>>>(out, Mubf, Munorm, out);
}